// Round 1
// baseline (363.082 us; speedup 1.0000x reference)
//
#include <hip/hip_runtime.h>
#include <hip/hip_bf16.h>
#include <stdint.h>

#define NH 16
#define DM 1024
#define DKV 64
#define BB 4
#define LL 2048
#define MT (BB*LL)   // 8192 rows total

typedef __bf16 bf16;
typedef __bf16 bf16x8 __attribute__((ext_vector_type(8)));
typedef float f32x4 __attribute__((ext_vector_type(4)));

__device__ __forceinline__ void gload_lds16(const void* g, void* l) {
  __builtin_amdgcn_global_load_lds(
      (const __attribute__((address_space(1))) unsigned int*)g,
      (__attribute__((address_space(3))) unsigned int*)l, 16, 0, 0);
}

__device__ __forceinline__ unsigned short bfbits(float x) {
  bf16 b = (bf16)x;
  return __builtin_bit_cast(unsigned short, b);
}

// ---------------- cast f32 -> bf16, 8 elems/thread ----------------
__global__ __launch_bounds__(256) void cast_f32_to_bf16(const float* __restrict__ in,
                                                        bf16* __restrict__ out, int n8) {
  int i = blockIdx.x * blockDim.x + threadIdx.x;
  if (i >= n8) return;
  const float4* p = (const float4*)in + (size_t)i * 2;
  float4 a = p[0], b = p[1];
  bf16x8 r;
  r[0] = (bf16)a.x; r[1] = (bf16)a.y; r[2] = (bf16)a.z; r[3] = (bf16)a.w;
  r[4] = (bf16)b.x; r[5] = (bf16)b.y; r[6] = (bf16)b.z; r[7] = (bf16)b.w;
  *((bf16x8*)out + i) = r;
}

// ---------------- repack w[h][d][kk] (f32) -> wt[h*64+kk][d] (bf16) ----------------
__global__ __launch_bounds__(256) void repack_w(const float* __restrict__ w0, const float* __restrict__ w1,
                                                const float* __restrict__ w2,
                                                bf16* __restrict__ o0, bf16* __restrict__ o1,
                                                bf16* __restrict__ o2) {
  const float* w = blockIdx.z == 0 ? w0 : (blockIdx.z == 1 ? w1 : w2);
  bf16* o = blockIdx.z == 0 ? o0 : (blockIdx.z == 1 ? o1 : o2);
  __shared__ float t[64][65];
  int h = blockIdx.y, d0 = blockIdx.x * 64;
  const float* src = w + ((size_t)h * DM + d0) * DKV;
  for (int i = threadIdx.x; i < 64 * 64; i += 256) {
    int r = i >> 6, c = i & 63;
    t[r][c] = src[(size_t)r * DKV + c];     // coalesced over c (=kk)
  }
  __syncthreads();
  for (int i = threadIdx.x; i < 64 * 64; i += 256) {
    int kk = i >> 6, d = i & 63;
    o[((size_t)(h * 64 + kk)) * DM + d0 + d] = (bf16)t[d][kk];  // coalesced over d
  }
}

// ---------------- GEMM: C[m][n] = sum_k A[m][k] * Bt[n][k]  (M=8192,N=1024,K=1024) ---------
// MODE 0: out bf16 natural, scale 1/32 (qh)
// MODE 1: out bf16 natural (kh)
// MODE 2: out bf16 transposed Vt[(h*4+b)*64+dv][s] (vh)
// MODE 3: out f32 natural + bias (final projection)
template <int MODE>
__global__ __launch_bounds__(256) void gemm_bt(const bf16* __restrict__ A, const bf16* __restrict__ Bt,
                                               void* __restrict__ Out, const float* __restrict__ bias) {
  __shared__ bf16 sA[128 * 64];
  __shared__ bf16 sB[128 * 64];
  const int tid = threadIdx.x;
  const int w = tid >> 6, l = tid & 63;
  const int c = l & 15, g4 = l >> 4;
  const int wm = w >> 1, wn = w & 1;
  const int m0 = blockIdx.y * 128, n0 = blockIdx.x * 128;

  f32x4 acc[4][4] = {};
  for (int kt = 0; kt < 1024; kt += 64) {
#pragma unroll
    for (int i = 0; i < 4; ++i) {
      int blk = i * 4 + w;                 // 0..15, 1KB each
      int row = blk * 8 + (l >> 3);        // 0..127
      int g = (l & 7) ^ (row & 7);         // inverse-swizzled source granule
      gload_lds16(A + ((size_t)(m0 + row)) * 1024 + kt + g * 8, (char*)sA + blk * 1024);
      gload_lds16(Bt + ((size_t)(n0 + row)) * 1024 + kt + g * 8, (char*)sB + blk * 1024);
    }
    __syncthreads();
#pragma unroll
    for (int ks = 0; ks < 2; ++ks) {
      bf16x8 af[4], bfr[4];
#pragma unroll
      for (int x = 0; x < 4; ++x) {
        int ar = wm * 64 + x * 16 + c;
        af[x] = *(const bf16x8*)((const char*)sA + ar * 128 + (((ks * 4 + g4) ^ (ar & 7)) * 16));
        int br = wn * 64 + x * 16 + c;
        bfr[x] = *(const bf16x8*)((const char*)sB + br * 128 + (((ks * 4 + g4) ^ (br & 7)) * 16));
      }
#pragma unroll
      for (int x = 0; x < 4; ++x)
#pragma unroll
        for (int y = 0; y < 4; ++y)
          acc[x][y] = __builtin_amdgcn_mfma_f32_16x16x32_bf16(af[x], bfr[y], acc[x][y], 0, 0, 0);
    }
    __syncthreads();
  }

  const int mm = m0 + wm * 64, nn = n0 + wn * 64;
  if constexpr (MODE == 0 || MODE == 1) {
    bf16* O = (bf16*)Out;
    const float s = (MODE == 0) ? 0.03125f : 1.0f;  // fold 1/sqrt(1024)
#pragma unroll
    for (int x = 0; x < 4; ++x)
#pragma unroll
      for (int y = 0; y < 4; ++y)
#pragma unroll
        for (int r = 0; r < 4; ++r) {
          int m = mm + x * 16 + g4 * 4 + r;
          int n = nn + y * 16 + c;
          O[(size_t)m * 1024 + n] = (bf16)(acc[x][y][r] * s);
        }
  } else if constexpr (MODE == 2) {
    bf16* O = (bf16*)Out;  // Vt[(h*4+b)*64+dv][s]
#pragma unroll
    for (int x = 0; x < 4; ++x)
#pragma unroll
      for (int y = 0; y < 4; ++y) {
        int mb = mm + x * 16 + g4 * 4;     // 4 consecutive s
        int n = nn + y * 16 + c;
        int b = mb >> 11, sidx = mb & 2047;
        int h = n >> 6, dv = n & 63;
        unsigned int u0 = bfbits(acc[x][y][0]) | ((unsigned int)bfbits(acc[x][y][1]) << 16);
        unsigned int u1 = bfbits(acc[x][y][2]) | ((unsigned int)bfbits(acc[x][y][3]) << 16);
        *(uint2*)(O + ((size_t)((h * 4 + b) * 64 + dv)) * LL + sidx) = make_uint2(u0, u1);
      }
  } else {
    float* O = (float*)Out;
#pragma unroll
    for (int x = 0; x < 4; ++x)
#pragma unroll
      for (int y = 0; y < 4; ++y)
#pragma unroll
        for (int r = 0; r < 4; ++r) {
          int m = mm + x * 16 + g4 * 4 + r;
          int n = nn + y * 16 + c;
          O[(size_t)m * 1024 + n] = acc[x][y][r] + bias[n];
        }
  }
}

// ---------------- flash attention ----------------
// grid (16 qtiles, 64 bh); block 256 (4 waves, 32 q-rows each)
__global__ __launch_bounds__(256) void attn_kernel(const bf16* __restrict__ qh, const bf16* __restrict__ kh,
                                                   const bf16* __restrict__ vt, bf16* __restrict__ o) {
  __shared__ bf16 sK[64 * 64];      // [kv][d] swizzled
  __shared__ bf16 sV[64 * 64];      // [dv][kv] swizzled
  __shared__ bf16 sP[4][32 * 64];   // per-wave P [q][kv] swizzled
  const int tid = threadIdx.x, w = tid >> 6, l = tid & 63;
  const int c = l & 15, g4 = l >> 4;
  const int bh = blockIdx.y, b = bh & 3, h = bh >> 2;
  const int q0 = blockIdx.x * 128 + w * 32;

  const bf16* qbase = qh + ((size_t)(b * LL)) * DM + h * 64;
  const bf16* kbase = kh + ((size_t)(b * LL)) * DM + h * 64;
  const bf16* vbase = vt + ((size_t)((h * 4 + b) * 64)) * LL;

  bf16x8 qf[2][2];
#pragma unroll
  for (int x = 0; x < 2; ++x)
#pragma unroll
    for (int ks = 0; ks < 2; ++ks)
      qf[x][ks] = *(const bf16x8*)(qbase + (size_t)(q0 + x * 16 + c) * DM + ks * 32 + g4 * 8);

  float mrow[2][4], lrow[2][4];
  f32x4 oacc[2][4] = {};
#pragma unroll
  for (int x = 0; x < 2; ++x)
#pragma unroll
    for (int r = 0; r < 4; ++r) { mrow[x][r] = -1e30f; lrow[x][r] = 0.f; }

  for (int kv0 = 0; kv0 < LL; kv0 += 64) {
#pragma unroll
    for (int i = 0; i < 2; ++i) {
      int blk = i * 4 + w;               // 0..7
      int row = blk * 8 + (l >> 3);      // 0..63
      int g = (l & 7) ^ (row & 7);
      gload_lds16(kbase + (size_t)(kv0 + row) * DM + g * 8, (char*)sK + blk * 1024);
      gload_lds16(vbase + (size_t)row * LL + kv0 + g * 8, (char*)sV + blk * 1024);
    }
    __syncthreads();

    // S = Q K^T (scale already folded into qh)
    f32x4 sf[2][4] = {};
#pragma unroll
    for (int ks = 0; ks < 2; ++ks) {
      bf16x8 kf[4];
#pragma unroll
      for (int y = 0; y < 4; ++y) {
        int kr = y * 16 + c;
        kf[y] = *(const bf16x8*)((const char*)sK + kr * 128 + (((ks * 4 + g4) ^ (kr & 7)) * 16));
      }
#pragma unroll
      for (int x = 0; x < 2; ++x)
#pragma unroll
        for (int y = 0; y < 4; ++y)
          sf[x][y] = __builtin_amdgcn_mfma_f32_16x16x32_bf16(qf[x][ks], kf[y], sf[x][y], 0, 0, 0);
    }

    // online softmax (wave-parallel, shfl_xor over the 16 lanes holding a row)
#pragma unroll
    for (int x = 0; x < 2; ++x)
#pragma unroll
      for (int r = 0; r < 4; ++r) {
        float tm = fmaxf(fmaxf(sf[x][0][r], sf[x][1][r]), fmaxf(sf[x][2][r], sf[x][3][r]));
        tm = fmaxf(tm, __shfl_xor(tm, 1));
        tm = fmaxf(tm, __shfl_xor(tm, 2));
        tm = fmaxf(tm, __shfl_xor(tm, 4));
        tm = fmaxf(tm, __shfl_xor(tm, 8));
        float mn = fmaxf(mrow[x][r], tm);
        float al = __expf(mrow[x][r] - mn);
        mrow[x][r] = mn;
        float rs = 0.f;
#pragma unroll
        for (int y = 0; y < 4; ++y) {
          float p = __expf(sf[x][y][r] - mn);
          sf[x][y][r] = p;
          rs += p;
        }
        rs += __shfl_xor(rs, 1); rs += __shfl_xor(rs, 2);
        rs += __shfl_xor(rs, 4); rs += __shfl_xor(rs, 8);
        lrow[x][r] = lrow[x][r] * al + rs;
#pragma unroll
        for (int y = 0; y < 4; ++y) oacc[x][y][r] *= al;
      }

    // P -> per-wave LDS (bf16, swizzled), then redistribute as A-frags
#pragma unroll
    for (int x = 0; x < 2; ++x)
#pragma unroll
      for (int y = 0; y < 4; ++y)
#pragma unroll
        for (int r = 0; r < 4; ++r) {
          int qr = x * 16 + g4 * 4 + r;   // 0..31
          int kv = y * 16 + c;            // 0..63
          int byte = qr * 128 + ((((kv >> 3)) ^ (qr & 7)) * 16) + (kv & 7) * 2;
          *(bf16*)((char*)sP[w] + byte) = (bf16)sf[x][y][r];
        }
    asm volatile("s_waitcnt lgkmcnt(0)" ::: "memory");
    __builtin_amdgcn_sched_barrier(0);

    // O += P V
#pragma unroll
    for (int kf2 = 0; kf2 < 2; ++kf2) {
      bf16x8 pa[2], vb[4];
#pragma unroll
      for (int x = 0; x < 2; ++x) {
        int pr = x * 16 + c;
        pa[x] = *(const bf16x8*)((const char*)sP[w] + pr * 128 + (((kf2 * 4 + g4) ^ (pr & 7)) * 16));
      }
#pragma unroll
      for (int y = 0; y < 4; ++y) {
        int vr = y * 16 + c;
        vb[y] = *(const bf16x8*)((const char*)sV + vr * 128 + (((kf2 * 4 + g4) ^ (vr & 7)) * 16));
      }
#pragma unroll
      for (int x = 0; x < 2; ++x)
#pragma unroll
        for (int y = 0; y < 4; ++y)
          oacc[x][y] = __builtin_amdgcn_mfma_f32_16x16x32_bf16(pa[x], vb[y], oacc[x][y], 0, 0, 0);
    }
    __syncthreads();
  }

  bf16* ob = o + ((size_t)(b * LL)) * DM + h * 64;
#pragma unroll
  for (int x = 0; x < 2; ++x)
#pragma unroll
    for (int y = 0; y < 4; ++y)
#pragma unroll
      for (int r = 0; r < 4; ++r) {
        int qq = q0 + x * 16 + g4 * 4 + r;
        int nn = y * 16 + c;
        ob[(size_t)qq * DM + nn] = (bf16)(oacc[x][y][r] / lrow[x][r]);
      }
}

extern "C" void kernel_launch(void* const* d_in, const int* in_sizes, int n_in,
                              void* d_out, int out_size, void* d_ws, size_t ws_size,
                              hipStream_t stream) {
  const float* q  = (const float*)d_in[0];
  const float* k  = (const float*)d_in[1];
  const float* v  = (const float*)d_in[2];
  const float* wq = (const float*)d_in[3];
  const float* wk = (const float*)d_in[4];
  const float* wv = (const float*)d_in[5];
  const float* pw = (const float*)d_in[6];
  const float* pb = (const float*)d_in[7];
  float* out = (float*)d_out;

  char* ws = (char*)d_ws;
  const size_t SX = (size_t)MT * DM * 2;   // 16.8 MB
  const size_t SW = (size_t)DM * DM * 2;   // 2 MB
  bf16* Xq  = (bf16*)(ws);
  bf16* Xk  = (bf16*)(ws + SX);
  bf16* Xv  = (bf16*)(ws + 2 * SX);
  bf16* Wqt = (bf16*)(ws + 3 * SX);
  bf16* Wkt = (bf16*)(ws + 3 * SX + SW);
  bf16* Wvt = (bf16*)(ws + 3 * SX + 2 * SW);
  bf16* Wp  = (bf16*)(ws + 3 * SX + 3 * SW);
  bf16* QH  = (bf16*)(ws + 3 * SX + 4 * SW);
  bf16* KH  = (bf16*)(ws + 4 * SX + 4 * SW);
  bf16* VT  = (bf16*)(ws + 5 * SX + 4 * SW);
  bf16* OO  = Xq;  // reuse: Xq dead after gemm<0>

  const int nx8 = MT * DM / 8;   // 1048576
  cast_f32_to_bf16<<<dim3(nx8 / 256), 256, 0, stream>>>(q, Xq, nx8);
  cast_f32_to_bf16<<<dim3(nx8 / 256), 256, 0, stream>>>(k, Xk, nx8);
  cast_f32_to_bf16<<<dim3(nx8 / 256), 256, 0, stream>>>(v, Xv, nx8);
  const int nw8 = DM * DM / 8;   // 131072
  cast_f32_to_bf16<<<dim3(nw8 / 256), 256, 0, stream>>>(pw, Wp, nw8);
  repack_w<<<dim3(16, 16, 3), 256, 0, stream>>>(wq, wk, wv, Wqt, Wkt, Wvt);

  gemm_bt<0><<<dim3(8, 64), 256, 0, stream>>>(Xq, Wqt, QH, nullptr);
  gemm_bt<1><<<dim3(8, 64), 256, 0, stream>>>(Xk, Wkt, KH, nullptr);
  gemm_bt<2><<<dim3(8, 64), 256, 0, stream>>>(Xv, Wvt, VT, nullptr);

  attn_kernel<<<dim3(16, 64), 256, 0, stream>>>(QH, KH, VT, OO);

  gemm_bt<3><<<dim3(8, 64), 256, 0, stream>>>(OO, Wp, out, pb);
}

// Round 2
// 267.139 us; speedup vs baseline: 1.3591x; 1.3591x over previous
//
#include <hip/hip_runtime.h>
#include <hip/hip_bf16.h>
#include <stdint.h>

#define NH 16
#define DM 1024
#define DKV 64
#define BB 4
#define LL 2048
#define MT (BB*LL)   // 8192 rows total

typedef __bf16 bf16;
typedef __bf16 bf16x8 __attribute__((ext_vector_type(8)));
typedef float f32x4 __attribute__((ext_vector_type(4)));
typedef float f32x16 __attribute__((ext_vector_type(16)));
typedef unsigned int u32x2 __attribute__((ext_vector_type(2)));
typedef unsigned int u32x4 __attribute__((ext_vector_type(4)));

__device__ __forceinline__ void gload_lds16(const void* g, void* l) {
  __builtin_amdgcn_global_load_lds(
      (const __attribute__((address_space(1))) unsigned int*)g,
      (__attribute__((address_space(3))) unsigned int*)l, 16, 0, 0);
}

__device__ __forceinline__ unsigned short bfbits(float x) {
  bf16 b = (bf16)x;
  return __builtin_bit_cast(unsigned short, b);
}

#if defined(__has_builtin)
#if __has_builtin(__builtin_amdgcn_permlane32_swap)
#define HAVE_PLSWAP 1
#endif
#endif

// swap: r.x = (lane<32)? a : b[partner];  r.y = (lane<32)? a[partner] : b
__device__ __forceinline__ u32x2 plswap(unsigned int a, unsigned int b, int hi) {
#ifdef HAVE_PLSWAP
  auto rr = __builtin_amdgcn_permlane32_swap(a, b, false, false);
  u32x2 r; r.x = rr[0]; r.y = rr[1];
  return r;
#else
  unsigned int pa = (unsigned int)__shfl_xor((int)a, 32);
  unsigned int pb_ = (unsigned int)__shfl_xor((int)b, 32);
  u32x2 r;
  r.x = hi ? pb_ : a;
  r.y = hi ? b : pa;
  return r;
#endif
}

// ---------------- cast f32 -> bf16, 8 elems/thread ----------------
__global__ __launch_bounds__(256) void cast_f32_to_bf16(const float* __restrict__ in,
                                                        bf16* __restrict__ out, int n8) {
  int i = blockIdx.x * blockDim.x + threadIdx.x;
  if (i >= n8) return;
  const float4* p = (const float4*)in + (size_t)i * 2;
  float4 a = p[0], b = p[1];
  bf16x8 r;
  r[0] = (bf16)a.x; r[1] = (bf16)a.y; r[2] = (bf16)a.z; r[3] = (bf16)a.w;
  r[4] = (bf16)b.x; r[5] = (bf16)b.y; r[6] = (bf16)b.z; r[7] = (bf16)b.w;
  *((bf16x8*)out + i) = r;
}

// ---------------- repack w[h][d][kk] (f32) -> wt[h*64+kk][d] (bf16) ----------------
__global__ __launch_bounds__(256) void repack_w(const float* __restrict__ w0, const float* __restrict__ w1,
                                                const float* __restrict__ w2,
                                                bf16* __restrict__ o0, bf16* __restrict__ o1,
                                                bf16* __restrict__ o2) {
  const float* w = blockIdx.z == 0 ? w0 : (blockIdx.z == 1 ? w1 : w2);
  bf16* o = blockIdx.z == 0 ? o0 : (blockIdx.z == 1 ? o1 : o2);
  __shared__ float t[64][65];
  int h = blockIdx.y, d0 = blockIdx.x * 64;
  const float* src = w + ((size_t)h * DM + d0) * DKV;
  for (int i = threadIdx.x; i < 64 * 64; i += 256) {
    int r = i >> 6, c = i & 63;
    t[r][c] = src[(size_t)r * DKV + c];
  }
  __syncthreads();
  for (int i = threadIdx.x; i < 64 * 64; i += 256) {
    int kk = i >> 6, d = i & 63;
    o[((size_t)(h * 64 + kk)) * DM + d0 + d] = (bf16)t[d][kk];
  }
}

// ---------------- GEMM: C[m][n] = sum_k A[m][k] * Bt[n][k] ----------------
template <int MODE>
__global__ __launch_bounds__(256) void gemm_bt(const bf16* __restrict__ A, const bf16* __restrict__ Bt,
                                               void* __restrict__ Out, const float* __restrict__ bias) {
  __shared__ bf16 sA[128 * 64];
  __shared__ bf16 sB[128 * 64];
  const int tid = threadIdx.x;
  const int w = tid >> 6, l = tid & 63;
  const int c = l & 15, g4 = l >> 4;
  const int wm = w >> 1, wn = w & 1;
  const int m0 = blockIdx.y * 128, n0 = blockIdx.x * 128;

  f32x4 acc[4][4] = {};
  for (int kt = 0; kt < 1024; kt += 64) {
#pragma unroll
    for (int i = 0; i < 4; ++i) {
      int blk = i * 4 + w;
      int row = blk * 8 + (l >> 3);
      int g = (l & 7) ^ (row & 7);
      gload_lds16(A + ((size_t)(m0 + row)) * 1024 + kt + g * 8, (char*)sA + blk * 1024);
      gload_lds16(Bt + ((size_t)(n0 + row)) * 1024 + kt + g * 8, (char*)sB + blk * 1024);
    }
    __syncthreads();
#pragma unroll
    for (int ks = 0; ks < 2; ++ks) {
      bf16x8 af[4], bfr[4];
#pragma unroll
      for (int x = 0; x < 4; ++x) {
        int ar = wm * 64 + x * 16 + c;
        af[x] = *(const bf16x8*)((const char*)sA + ar * 128 + (((ks * 4 + g4) ^ (ar & 7)) * 16));
        int br = wn * 64 + x * 16 + c;
        bfr[x] = *(const bf16x8*)((const char*)sB + br * 128 + (((ks * 4 + g4) ^ (br & 7)) * 16));
      }
#pragma unroll
      for (int x = 0; x < 4; ++x)
#pragma unroll
        for (int y = 0; y < 4; ++y)
          acc[x][y] = __builtin_amdgcn_mfma_f32_16x16x32_bf16(af[x], bfr[y], acc[x][y], 0, 0, 0);
    }
    __syncthreads();
  }

  const int mm = m0 + wm * 64, nn = n0 + wn * 64;
  if constexpr (MODE == 0 || MODE == 1) {
    bf16* O = (bf16*)Out;
    const float s = (MODE == 0) ? 0.03125f : 1.0f;
#pragma unroll
    for (int x = 0; x < 4; ++x)
#pragma unroll
      for (int y = 0; y < 4; ++y)
#pragma unroll
        for (int r = 0; r < 4; ++r) {
          int m = mm + x * 16 + g4 * 4 + r;
          int n = nn + y * 16 + c;
          O[(size_t)m * 1024 + n] = (bf16)(acc[x][y][r] * s);
        }
  } else if constexpr (MODE == 2) {
    bf16* O = (bf16*)Out;  // Vt[(h*4+b)*64+dv][s]
#pragma unroll
    for (int x = 0; x < 4; ++x)
#pragma unroll
      for (int y = 0; y < 4; ++y) {
        int mb = mm + x * 16 + g4 * 4;
        int n = nn + y * 16 + c;
        int b = mb >> 11, sidx = mb & 2047;
        int h = n >> 6, dv = n & 63;
        unsigned int u0 = bfbits(acc[x][y][0]) | ((unsigned int)bfbits(acc[x][y][1]) << 16);
        unsigned int u1 = bfbits(acc[x][y][2]) | ((unsigned int)bfbits(acc[x][y][3]) << 16);
        *(uint2*)(O + ((size_t)((h * 4 + b) * 64 + dv)) * LL + sidx) = make_uint2(u0, u1);
      }
  } else {
    float* O = (float*)Out;
#pragma unroll
    for (int x = 0; x < 4; ++x)
#pragma unroll
      for (int y = 0; y < 4; ++y)
#pragma unroll
        for (int r = 0; r < 4; ++r) {
          int m = mm + x * 16 + g4 * 4 + r;
          int n = nn + y * 16 + c;
          O[(size_t)m * 1024 + n] = acc[x][y][r] + bias[n];
        }
  }
}

// ---------------- flash attention, swapped-QK^T in-register softmax ----------------
// grid (16 qtiles of 128, 64 bh); block 256 (4 waves, 32 q-rows each)
__global__ __launch_bounds__(256) void attn_kernel(const bf16* __restrict__ qh, const bf16* __restrict__ kh,
                                                   const bf16* __restrict__ vt, bf16* __restrict__ o) {
  __shared__ bf16 sK[2][64 * 64];   // [kv][d] swizzled
  __shared__ bf16 sV[2][64 * 64];   // [dv][kv] swizzled
  const int tid = threadIdx.x, w = tid >> 6, l = tid & 63;
  const int c = l & 31, hi = l >> 5;
  const int bh = blockIdx.y, b = bh & 3, h = bh >> 2;
  const int q0 = blockIdx.x * 128 + w * 32;

  const bf16* qbase = qh + ((size_t)(b * LL)) * DM + h * 64;
  const bf16* kbase = kh + ((size_t)(b * LL)) * DM + h * 64;
  const bf16* vbase = vt + ((size_t)((h * 4 + b) * 64)) * LL;

  // Q fragments (B-operand): lane holds Q[q=q0+c][d=ks*16+hi*8 .. +8]
  bf16x8 qf[4];
#pragma unroll
  for (int ks = 0; ks < 4; ++ks)
    qf[ks] = *(const bf16x8*)(qbase + (size_t)(q0 + c) * DM + ks * 16 + hi * 8);

  f32x16 oaccT[2] = {};   // O^T tiles: [dv 0..31] and [dv 32..63], col q = q0+c
  float mrow = -1e30f, lrow = 0.f;

  auto STAGE = [&](int bufi, int kv0) {
#pragma unroll
    for (int j = 0; j < 2; ++j) {
      int gi = w * 128 + j * 64 + l;            // granule 0..511
      int row = gi >> 3;
      int g = (gi & 7) ^ (row & 7);             // inverse-swizzled source granule
      gload_lds16(kbase + (size_t)(kv0 + row) * DM + g * 8,
                  (char*)sK[bufi] + (w * 128 + j * 64) * 16);
      gload_lds16(vbase + (size_t)row * LL + kv0 + g * 8,
                  (char*)sV[bufi] + (w * 128 + j * 64) * 16);
    }
  };

  int buf = 0;
  STAGE(0, 0);
  asm volatile("s_waitcnt vmcnt(0)" ::: "memory");
  __syncthreads();

  for (int it = 0; it < LL / 64; ++it) {
    if (it < LL / 64 - 1) STAGE(buf ^ 1, (it + 1) * 64);

    // ---- S^T = K · Q^T  (two 32-kv tiles) ----
    const char* Kb = (const char*)sK[buf];
    f32x16 st0 = {}, st1 = {};
    __builtin_amdgcn_s_setprio(1);
#pragma unroll
    for (int ks = 0; ks < 4; ++ks) {
      int slot = ((ks * 2 + hi) ^ (c & 7)) * 16;
      bf16x8 k0 = *(const bf16x8*)(Kb + c * 128 + slot);
      bf16x8 k1 = *(const bf16x8*)(Kb + (32 + c) * 128 + slot);
      st0 = __builtin_amdgcn_mfma_f32_32x32x16_bf16(k0, qf[ks], st0, 0, 0, 0);
      st1 = __builtin_amdgcn_mfma_f32_32x32x16_bf16(k1, qf[ks], st1, 0, 0, 0);
    }
    __builtin_amdgcn_s_setprio(0);

    // ---- online softmax: lane owns q=q0+c; kv slices in-register ----
    float tm = st0[0];
#pragma unroll
    for (int r = 1; r < 16; ++r) tm = fmaxf(tm, st0[r]);
#pragma unroll
    for (int r = 0; r < 16; ++r) tm = fmaxf(tm, st1[r]);
    tm = fmaxf(tm, __shfl_xor(tm, 32));
    float mn = fmaxf(mrow, tm);
    float al = __expf(mrow - mn);
    mrow = mn;
    float rs = 0.f;
#pragma unroll
    for (int r = 0; r < 16; ++r) { st0[r] = __expf(st0[r] - mn); rs += st0[r]; }
#pragma unroll
    for (int r = 0; r < 16; ++r) { st1[r] = __expf(st1[r] - mn); rs += st1[r]; }
    rs += __shfl_xor(rs, 32);
    lrow = lrow * al + rs;
    oaccT[0] *= al;
    oaccT[1] *= al;

    // ---- P -> bf16 fragments via pack + permlane32_swap ----
    bf16x8 pb[4];
#pragma unroll
    for (int t = 0; t < 2; ++t) {
      const f32x16& st = t ? st1 : st0;
      unsigned int u[4][2];
#pragma unroll
      for (int g2 = 0; g2 < 4; ++g2) {
        u[g2][0] = (unsigned int)bfbits(st[4 * g2 + 0]) | ((unsigned int)bfbits(st[4 * g2 + 1]) << 16);
        u[g2][1] = (unsigned int)bfbits(st[4 * g2 + 2]) | ((unsigned int)bfbits(st[4 * g2 + 3]) << 16);
      }
      u32x2 s0 = plswap(u[0][0], u[1][0], hi);
      u32x2 s1 = plswap(u[0][1], u[1][1], hi);
      u32x4 w0; w0.x = s0.x; w0.y = s1.x; w0.z = s0.y; w0.w = s1.y;
      pb[2 * t] = __builtin_bit_cast(bf16x8, w0);
      u32x2 s2 = plswap(u[2][0], u[3][0], hi);
      u32x2 s3 = plswap(u[2][1], u[3][1], hi);
      u32x4 w1; w1.x = s2.x; w1.y = s3.x; w1.z = s2.y; w1.w = s3.y;
      pb[2 * t + 1] = __builtin_bit_cast(bf16x8, w1);
    }

    // ---- O^T += V^T · P^T ----
    const char* Vb = (const char*)sV[buf];
    __builtin_amdgcn_s_setprio(1);
#pragma unroll
    for (int ks = 0; ks < 4; ++ks) {
      int slot = ((ks * 2 + hi) ^ (c & 7)) * 16;
      bf16x8 v0 = *(const bf16x8*)(Vb + c * 128 + slot);
      bf16x8 v1 = *(const bf16x8*)(Vb + (32 + c) * 128 + slot);
      oaccT[0] = __builtin_amdgcn_mfma_f32_32x32x16_bf16(v0, pb[ks], oaccT[0], 0, 0, 0);
      oaccT[1] = __builtin_amdgcn_mfma_f32_32x32x16_bf16(v1, pb[ks], oaccT[1], 0, 0, 0);
    }
    __builtin_amdgcn_s_setprio(0);

    asm volatile("s_waitcnt vmcnt(0)" ::: "memory");
    __syncthreads();
    buf ^= 1;
  }

  // ---- epilogue: O[q][dv] = oaccT / lrow ----
  bf16* ob = o + ((size_t)(b * LL)) * DM + h * 64;
  float inv = 1.0f / lrow;
#pragma unroll
  for (int dt = 0; dt < 2; ++dt)
#pragma unroll
    for (int rg = 0; rg < 4; ++rg) {
      int dv0 = dt * 32 + rg * 8 + hi * 4;
      unsigned int u0 = (unsigned int)bfbits(oaccT[dt][rg * 4 + 0] * inv) |
                        ((unsigned int)bfbits(oaccT[dt][rg * 4 + 1] * inv) << 16);
      unsigned int u1 = (unsigned int)bfbits(oaccT[dt][rg * 4 + 2] * inv) |
                        ((unsigned int)bfbits(oaccT[dt][rg * 4 + 3] * inv) << 16);
      *(uint2*)(ob + (size_t)(q0 + c) * DM + dv0) = make_uint2(u0, u1);
    }
}

extern "C" void kernel_launch(void* const* d_in, const int* in_sizes, int n_in,
                              void* d_out, int out_size, void* d_ws, size_t ws_size,
                              hipStream_t stream) {
  const float* q  = (const float*)d_in[0];
  const float* k  = (const float*)d_in[1];
  const float* v  = (const float*)d_in[2];
  const float* wq = (const float*)d_in[3];
  const float* wk = (const float*)d_in[4];
  const float* wv = (const float*)d_in[5];
  const float* pw = (const float*)d_in[6];
  const float* pb = (const float*)d_in[7];
  float* out = (float*)d_out;

  char* ws = (char*)d_ws;
  const size_t SX = (size_t)MT * DM * 2;   // 16.8 MB
  const size_t SW = (size_t)DM * DM * 2;   // 2 MB
  bf16* Xq  = (bf16*)(ws);
  bf16* Xk  = (bf16*)(ws + SX);
  bf16* Xv  = (bf16*)(ws + 2 * SX);
  bf16* Wqt = (bf16*)(ws + 3 * SX);
  bf16* Wkt = (bf16*)(ws + 3 * SX + SW);
  bf16* Wvt = (bf16*)(ws + 3 * SX + 2 * SW);
  bf16* Wp  = (bf16*)(ws + 3 * SX + 3 * SW);
  bf16* QH  = (bf16*)(ws + 3 * SX + 4 * SW);
  bf16* KH  = (bf16*)(ws + 4 * SX + 4 * SW);
  bf16* VT  = (bf16*)(ws + 5 * SX + 4 * SW);
  bf16* OO  = Xq;  // reuse: Xq dead after gemm<0>

  const int nx8 = MT * DM / 8;
  cast_f32_to_bf16<<<dim3(nx8 / 256), 256, 0, stream>>>(q, Xq, nx8);
  cast_f32_to_bf16<<<dim3(nx8 / 256), 256, 0, stream>>>(k, Xk, nx8);
  cast_f32_to_bf16<<<dim3(nx8 / 256), 256, 0, stream>>>(v, Xv, nx8);
  const int nw8 = DM * DM / 8;
  cast_f32_to_bf16<<<dim3(nw8 / 256), 256, 0, stream>>>(pw, Wp, nw8);
  repack_w<<<dim3(16, 16, 3), 256, 0, stream>>>(wq, wk, wv, Wqt, Wkt, Wvt);

  gemm_bt<0><<<dim3(8, 64), 256, 0, stream>>>(Xq, Wqt, QH, nullptr);
  gemm_bt<1><<<dim3(8, 64), 256, 0, stream>>>(Xk, Wkt, KH, nullptr);
  gemm_bt<2><<<dim3(8, 64), 256, 0, stream>>>(Xv, Wvt, VT, nullptr);

  attn_kernel<<<dim3(16, 64), 256, 0, stream>>>(QH, KH, VT, OO);

  gemm_bt<3><<<dim3(8, 64), 256, 0, stream>>>(OO, Wp, out, pb);
}